// Round 12
// baseline (102.939 us; speedup 1.0000x reference)
//
#include <hip/hip_runtime.h>
#include <hip/hip_bf16.h>
#include <math.h>

#define BATCH 512
#define EMBED 512
#define NCLS  100000
#define NT128 782          // ceil(100000/128) class tiles
#define NBLK  512          // 4 panels x 128 cgs

typedef __attribute__((ext_vector_type(4)))  float f32x4;
typedef __attribute__((ext_vector_type(16))) float f32x16;
typedef __attribute__((ext_vector_type(2)))  long  i64x2;

constexpr float kCOS_M = 0.8775825618903728f;   // cos(0.5)
constexpr float kSIN_M = 0.4794255386042030f;   // sin(0.5)
constexpr float kTHR   = -0.8775825618903728f;  // cos(pi-0.5)
constexpr float kMM    = 0.2397127693021015f;   // sin(pi-0.5)*0.5

#define BARRIER() asm volatile("s_waitcnt lgkmcnt(0)\n\ts_barrier" ::: "memory")

__device__ __forceinline__ unsigned cvt4(float a, float b, float c, float d) {
  int v = __builtin_amdgcn_cvt_pk_fp8_f32(a, b, 0, false);
  v = __builtin_amdgcn_cvt_pk_fp8_f32(c, d, v, true);
  return (unsigned)v;
}

// ---------------- K1: normalize embeddings -> fp8 x16, K-MAJOR layout ---------
// En8[t 0..15][hi 0..1][row 0..511][16B]; slot(t,hi) byte = half*8 + j holds
// element k = t*32 + half*16 + hi*8 + j. Lane l owns k = 8l..8l+7:
// t = l>>2, hi = l&1, half = (l>>1)&1.
__global__ void knorm_e(const float* __restrict__ E, unsigned char* __restrict__ En8) {
  int r = blockIdx.x;
  int l = threadIdx.x;
  const f32x4* src = (const f32x4*)(E + r * EMBED);
  f32x4 a = src[2 * l], b = src[2 * l + 1];
  float ss = a.x*a.x + a.y*a.y + a.z*a.z + a.w*a.w
           + b.x*b.x + b.y*b.y + b.z*b.z + b.w*b.w;
#pragma unroll
  for (int d = 1; d < 64; d <<= 1) ss += __shfl_xor(ss, d);
  float s = 16.0f / fmaxf(sqrtf(ss), 1e-12f);
  uint2 pk;
  pk.x = cvt4(a.x * s, a.y * s, a.z * s, a.w * s);
  pk.y = cvt4(b.x * s, b.y * s, b.z * s, b.w * s);
  int t = l >> 2, hi = l & 1, hf = (l >> 1) & 1;
  *(uint2*)(En8 + ((((t << 1) | hi) * 512 + r) << 4) + hf * 8) = pk;
}

// ---------------- K2: label-column cosine + margin in f32 ----------------
__global__ void klabel(const float* __restrict__ E, const float* __restrict__ W,
                       const int* __restrict__ labels,
                       float* __restrict__ lcos, float* __restrict__ lphi)
{
  int r = blockIdx.x * 8 + (threadIdx.x >> 6);
  int l = threadIdx.x & 63;
  int lbl = labels[r];
  const float* ep = E + (size_t)r * EMBED + l * 8;
  const float* wp = W + (size_t)lbl * EMBED + l * 8;
  f32x4 e0 = *(const f32x4*)ep, e1 = *(const f32x4*)(ep + 4);
  f32x4 w0 = *(const f32x4*)wp, w1 = *(const f32x4*)(wp + 4);
  float dot = e0.x*w0.x + e0.y*w0.y + e0.z*w0.z + e0.w*w0.w
            + e1.x*w1.x + e1.y*w1.y + e1.z*w1.z + e1.w*w1.w;
  float se = e0.x*e0.x + e0.y*e0.y + e0.z*e0.z + e0.w*e0.w
           + e1.x*e1.x + e1.y*e1.y + e1.z*e1.z + e1.w*e1.w;
  float sw = w0.x*w0.x + w0.y*w0.y + w0.z*w0.z + w0.w*w0.w
           + w1.x*w1.x + w1.y*w1.y + w1.z*w1.z + w1.w*w1.w;
#pragma unroll
  for (int d = 1; d < 64; d <<= 1) {
    dot += __shfl_xor(dot, d); se += __shfl_xor(se, d); sw += __shfl_xor(sw, d);
  }
  float cosv = dot / (fmaxf(sqrtf(se), 1e-12f) * fmaxf(sqrtf(sw), 1e-12f));
  float cc = fminf(fmaxf(cosv, -1.f), 1.f);
  float sine = sqrtf(fmaxf(1.f - cc * cc, 0.f));
  float phi = (cosv > kTHR) ? (cosv * kCOS_M - sine * kSIN_M) : (cosv - kMM);
  if (l == 0) { lcos[r] = 64.f * cosv; lphi[r] = 64.f * phi; }
}

// ---------------- K3: fused fp8 GEMM + fixed-max expsum --------------------
// 512 blocks (2/CU) = 4 panels x 128 cgs. BM=128, BN=128/phase, BK=64.
// A staged PER PHASE (8KB dbuf) via global_load_lds from L2-resident En8;
// B reg-staged -> cvt fp8 -> LDS dbuf (R11 schedule). One barrier per phase,
// vmcnt(4) before each compute guarantees the A-glds of this phase retired.
__global__ __launch_bounds__(512, 4) void kmain(
    const unsigned char* __restrict__ En8, const float* __restrict__ W,
    float* __restrict__ psum)
{
  __shared__ __align__(16) unsigned char Asm[2][8192];
  __shared__ __align__(16) unsigned char Bsm[2][8192];
  __shared__ float rowsum[128];
  __shared__ float smemS[2][128];

  int bid = blockIdx.x;
  int xcd = bid & 7;
  int panel = (bid >> 3) & 3;
  int grp = bid >> 5;                        // 0..15
  int cg = xcd | (grp << 3);                 // 0..127

  int tid = threadIdx.x;
  int w = tid >> 6, l = tid & 63;
  int wr = w >> 1, wc = w & 1;               // 4 row-waves x 2 col-waves
  int cl = l & 31, hi = l >> 5;
  int bcls = tid >> 2, bs = tid & 3;         // B staging: class 0..127, 16-float seg

  int nt = (cg < 14) ? 7 : 6;                // 782 = 6*128 + 14
  int nph = nt * 8;

  // ---- A per-phase staging: thread -> chunk c (0..3), row ar (0..127) ----
  int ac = tid >> 7, ar = tid & 127;
  auto stageA = [&](int q) {
    int t = ((q & 7) << 1) | (ac >> 1);
    int hh = ac & 1;
    const unsigned char* src = En8 + ((((t << 1) | hh) * 512 + panel * 128 + ar) << 4);
    __builtin_amdgcn_global_load_lds(
        (const __attribute__((address_space(1))) void*)src,
        (__attribute__((address_space(3))) void*)(&Asm[q & 1][tid * 16]), 16, 0, 0);
  };

  // ---- B staging: thread's 16 floats = k_local bs*16..bs*16+15 ----
  float ssq = 0.f;
  const int tp = bs >> 1, hf = bs & 1;
  const int wbase0 = (((tp << 1) | 0) * 128 + bcls) * 16 + hf * 8;   // hi=0 slot
  const int wbase1 = wbase0 + 2048;                                  // hi=1 slot

  f32x4 Ra[4], Rb[4];
  auto loadB = [&](int q, f32x4* R) {
    int T = q >> 3;
    int cls = (cg + (T << 7)) * 128 + bcls;
    if (cls >= NCLS) cls = NCLS - 1;
    const float* p = W + (size_t)cls * EMBED + ((q & 7) << 6) + (bs << 4);
#pragma unroll
    for (int i = 0; i < 4; ++i) R[i] = *(const f32x4*)(p + i * 4);
  };
  auto writeB = [&](int buf, f32x4* R) {
#pragma unroll
    for (int i = 0; i < 4; ++i)
      ssq += R[i].x*R[i].x + R[i].y*R[i].y + R[i].z*R[i].z + R[i].w*R[i].w;
    uint2 p0, p1;
    p0.x = cvt4(R[0].x*128.f, R[0].y*128.f, R[0].z*128.f, R[0].w*128.f);
    p0.y = cvt4(R[1].x*128.f, R[1].y*128.f, R[1].z*128.f, R[1].w*128.f);
    p1.x = cvt4(R[2].x*128.f, R[2].y*128.f, R[2].z*128.f, R[2].w*128.f);
    p1.y = cvt4(R[3].x*128.f, R[3].y*128.f, R[3].z*128.f, R[3].w*128.f);
    *(uint2*)(&Bsm[buf][wbase0]) = p0;   // hi=0 half
    *(uint2*)(&Bsm[buf][wbase1]) = p1;   // hi=1 half
  };

  f32x16 acc0, acc1, S;
#pragma unroll
  for (int e = 0; e < 16; ++e) { acc0[e] = 0.f; acc1[e] = 0.f; S[e] = 0.f; }

  const int aoff = hi * 2048 + (wr * 32 + cl) * 16;
  const int boff = hi * 2048 + (wc * 64 + cl) * 16;

  auto compute = [&](int buf) {
    const unsigned char* A = &Asm[buf][0];
    const unsigned char* B = &Bsm[buf][0];
    i64x2 a0  = *(const i64x2*)(A + aoff);
    i64x2 a1  = *(const i64x2*)(A + aoff + 4096);
    i64x2 b00 = *(const i64x2*)(B + boff);
    i64x2 b01 = *(const i64x2*)(B + boff + 512);
    i64x2 b10 = *(const i64x2*)(B + boff + 4096);
    i64x2 b11 = *(const i64x2*)(B + boff + 4096 + 512);
    __builtin_amdgcn_s_setprio(1);
    acc0 = __builtin_amdgcn_mfma_f32_32x32x16_fp8_fp8(a0[0], b00[0], acc0, 0, 0, 0);
    acc0 = __builtin_amdgcn_mfma_f32_32x32x16_fp8_fp8(a0[1], b00[1], acc0, 0, 0, 0);
    acc1 = __builtin_amdgcn_mfma_f32_32x32x16_fp8_fp8(a0[0], b01[0], acc1, 0, 0, 0);
    acc1 = __builtin_amdgcn_mfma_f32_32x32x16_fp8_fp8(a0[1], b01[1], acc1, 0, 0, 0);
    acc0 = __builtin_amdgcn_mfma_f32_32x32x16_fp8_fp8(a1[0], b10[0], acc0, 0, 0, 0);
    acc0 = __builtin_amdgcn_mfma_f32_32x32x16_fp8_fp8(a1[1], b10[1], acc0, 0, 0, 0);
    acc1 = __builtin_amdgcn_mfma_f32_32x32x16_fp8_fp8(a1[0], b11[0], acc1, 0, 0, 0);
    acc1 = __builtin_amdgcn_mfma_f32_32x32x16_fp8_fp8(a1[1], b11[1], acc1, 0, 0, 0);
    __builtin_amdgcn_s_setprio(0);
  };

  auto ssqred = [&]() {
    float sq = ssq;
    sq += __shfl_xor(sq, 1); sq += __shfl_xor(sq, 2);
    if (bs == 0) rowsum[bcls] = sq;
    ssq = 0.f;
  };

  auto epilogue = [&](int T) {
    int base = (cg + (T << 7)) * 128 + wc * 64;
    float rs0 = fmaxf(rowsum[wc * 64 + cl], 1e-30f);
    float rs1 = fmaxf(rowsum[wc * 64 + 32 + cl], 1e-30f);
    float rn0 = 0.03125f * rsqrtf(rs0);
    float rn1 = 0.03125f * rsqrtf(rs1);
    float vm0 = (base + cl < NCLS) ? 1.0f : 0.0f;
    float vm1 = (base + 32 + cl < NCLS) ? 1.0f : 0.0f;
#pragma unroll
    for (int e = 0; e < 16; ++e) {
      float u0 = __expf(fmaf(acc0[e], rn0, -64.0f));
      float u1 = __expf(fmaf(acc1[e], rn1, -64.0f));
      S[e] = fmaf(u0, vm0, fmaf(u1, vm1, S[e]));
      acc0[e] = 0.f; acc1[e] = 0.f;
    }
  };

  // ---- prologue: A(0) staged; Bsm[0] written; B(1),B(2) in regs ----
  stageA(0);
  loadB(0, Ra); loadB(1, Rb);
  asm volatile("s_waitcnt vmcnt(0)" ::: "memory");
  writeB(0, Ra);
  loadB(2, Ra);
  BARRIER();

  for (int p = 0; p < nph; p += 2) {
    // -------- even region p: stage phase p+1 (Rb), compute(p) on buf0 -----
    writeB(1, Rb);                 // Bsm[1] <- B(p+1); prev readers fenced
    stageA(p + 1);                 // Asm[1] <- A(p+1) (glds, unconditional)
    loadB(p + 3, Rb);              // regs <- B(p+3) (clamped, unconditional)
    if (((p + 1) & 7) == 7) ssqred();
    asm volatile("s_waitcnt vmcnt(4)" ::: "memory");   // all prev-region vm ops done
    compute(0);
    BARRIER();
    // -------- odd region p+1: stage phase p+2 (Ra), compute(p+1) on buf1 --
    writeB(0, Ra);
    stageA(p + 2);
    loadB(p + 4, Ra);
    asm volatile("s_waitcnt vmcnt(4)" ::: "memory");
    compute(1);
    if (((p + 1) & 7) == 7) epilogue((p + 1) >> 3);
    BARRIER();
  }

  // ---- fold S across the 32 class-lanes; combine the 2 col-waves ----
#pragma unroll
  for (int e = 0; e < 16; ++e) {
    float v = S[e];
    v += __shfl_xor(v, 1); v += __shfl_xor(v, 2); v += __shfl_xor(v, 4);
    v += __shfl_xor(v, 8); v += __shfl_xor(v, 16);
    S[e] = v;
  }
  __syncthreads();
  if (cl == 0) {
#pragma unroll
    for (int e = 0; e < 16; ++e) {
      int row = wr * 32 + (e & 3) + 8 * (e >> 2) + 4 * hi;
      smemS[wc][row] = S[e];
    }
  }
  __syncthreads();
  if (tid < 128) psum[bid * 128 + tid] = smemS[0][tid] + smemS[1][tid];
}

// ---------------- K4: reduce over the 8 XCD siblings of each (panel,grp) ----
__global__ void kred1(const float* __restrict__ psum, float* __restrict__ pp2) {
  int g = blockIdx.x;            // 0..63: panel = g>>4, grp = g&15
  int r = threadIdx.x;           // 128
  int panel = g >> 4, grp = g & 15;
  float s = 0.f;
#pragma unroll
  for (int x = 0; x < 8; ++x) {
    int bid = x | (panel << 3) | (grp << 5);
    s += psum[bid * 128 + r];
  }
  pp2[g * 128 + r] = s;
}

// ---------------- K5: final combine + label adjust + NLL mean ----------------
__global__ void kfinal(const float* __restrict__ pp2, const float* __restrict__ lcos,
                       const float* __restrict__ lphi, float* __restrict__ out)
{
  int tid = threadIdx.x;         // 512 = one thread per batch row
  int panel = tid >> 7, rl = tid & 127;
  float S = 0.f;
#pragma unroll
  for (int grp = 0; grp < 16; ++grp)
    S += pp2[(panel * 16 + grp) * 128 + rl];
  float lc = lcos[tid], lp = lphi[tid];
  S = S - __expf(lc - 64.f) + __expf(lp - 64.f);
  float nll = 64.f + __logf(S) - lp;
#pragma unroll
  for (int d = 1; d < 64; d <<= 1) nll += __shfl_xor(nll, d);
  __shared__ float sm[8];
  if ((tid & 63) == 0) sm[tid >> 6] = nll;
  __syncthreads();
  if (tid == 0) {
    float t = 0.f;
    for (int k = 0; k < 8; ++k) t += sm[k];
    out[0] = t * (1.0f / 512.0f);
  }
}

extern "C" void kernel_launch(void* const* d_in, const int* in_sizes, int n_in,
                              void* d_out, int out_size, void* d_ws, size_t ws_size,
                              hipStream_t stream)
{
  const float* E      = (const float*)d_in[0];
  const int*   labels = (const int*)d_in[1];
  const float* W      = (const float*)d_in[2];
  float* out = (float*)d_out;

  char* ws = (char*)d_ws;
  unsigned char* En8 = (unsigned char*)ws;              // 512*512 = 262144 B
  float* psum = (float*)(ws + 262144);                  // 512*128*4 = 262144 B
  float* pp2  = (float*)(ws + 524288);                  // 64*128*4 = 32768 B
  float* lcos = (float*)(ws + 557056);                  // 2048 B
  float* lphi = lcos + BATCH;                           // 2048 B

  knorm_e<<<BATCH, 64, 0, stream>>>(E, En8);
  klabel <<<64, 512, 0, stream>>>(E, W, labels, lcos, lphi);
  kmain  <<<NBLK, 512, 0, stream>>>(En8, W, psum);
  kred1  <<<64, 128, 0, stream>>>(psum, pp2);
  kfinal <<<1, 512, 0, stream>>>(pp2, lcos, lphi, out);
}

// Round 13
// 90.837 us; speedup vs baseline: 1.1332x; 1.1332x over previous
//
#include <hip/hip_runtime.h>
#include <hip/hip_bf16.h>
#include <math.h>

#define BATCH 512
#define EMBED 512
#define NCLS  100000
#define NT128 782          // ceil(100000/128) class tiles
#define NBLK  512          // 4 panels x 128 cgs

typedef __attribute__((ext_vector_type(4)))  float f32x4;
typedef __attribute__((ext_vector_type(16))) float f32x16;
typedef __attribute__((ext_vector_type(2)))  long  i64x2;

constexpr float kCOS_M = 0.8775825618903728f;   // cos(0.5)
constexpr float kSIN_M = 0.4794255386042030f;   // sin(0.5)
constexpr float kTHR   = -0.8775825618903728f;  // cos(pi-0.5)
constexpr float kMM    = 0.2397127693021015f;   // sin(pi-0.5)*0.5

#define BARRIER() asm volatile("s_waitcnt lgkmcnt(0)\n\ts_barrier" ::: "memory")

__device__ __forceinline__ unsigned cvt4(float a, float b, float c, float d) {
  int v = __builtin_amdgcn_cvt_pk_fp8_f32(a, b, 0, false);
  v = __builtin_amdgcn_cvt_pk_fp8_f32(c, d, v, true);
  return (unsigned)v;
}

// ---------------- K1: normalize embeddings -> fp8 x16, hi-split + XOR-swizzled ----
// (R10/R11 verbatim) Element k of row r: slotL = k[3]<<4 | k[8:5], half = k[4];
// physical 16B slot = slotL ^ (r&31); byte = half*8 + k[2:0].
__global__ void knorm_e(const float* __restrict__ E, unsigned char* __restrict__ En8) {
  int r = blockIdx.x;
  int l = threadIdx.x;                       // lane owns elems 8l..8l+7
  const f32x4* src = (const f32x4*)(E + r * EMBED);
  f32x4 a = src[2 * l], b = src[2 * l + 1];
  float ss = a.x*a.x + a.y*a.y + a.z*a.z + a.w*a.w
           + b.x*b.x + b.y*b.y + b.z*b.z + b.w*b.w;
#pragma unroll
  for (int d = 1; d < 64; d <<= 1) ss += __shfl_xor(ss, d);
  float s = 16.0f / fmaxf(sqrtf(ss), 1e-12f);
  uint2 pk;
  pk.x = cvt4(a.x * s, a.y * s, a.z * s, a.w * s);
  pk.y = cvt4(b.x * s, b.y * s, b.z * s, b.w * s);
  int slotL = (l & 1) * 16 + (l >> 2);
  int half  = (l >> 1) & 1;
  *(uint2*)(En8 + r * 512 + (((slotL ^ (r & 31)) << 4) | (half << 3))) = pk;
}

// ---------------- K2: label-column cosine + margin in f32 ----------------
__global__ void klabel(const float* __restrict__ E, const float* __restrict__ W,
                       const int* __restrict__ labels,
                       float* __restrict__ lcos, float* __restrict__ lphi)
{
  int r = blockIdx.x * 8 + (threadIdx.x >> 6);
  int l = threadIdx.x & 63;
  int lbl = labels[r];
  const float* ep = E + (size_t)r * EMBED + l * 8;
  const float* wp = W + (size_t)lbl * EMBED + l * 8;
  f32x4 e0 = *(const f32x4*)ep, e1 = *(const f32x4*)(ep + 4);
  f32x4 w0 = *(const f32x4*)wp, w1 = *(const f32x4*)(wp + 4);
  float dot = e0.x*w0.x + e0.y*w0.y + e0.z*w0.z + e0.w*w0.w
            + e1.x*w1.x + e1.y*w1.y + e1.z*w1.z + e1.w*w1.w;
  float se = e0.x*e0.x + e0.y*e0.y + e0.z*e0.z + e0.w*e0.w
           + e1.x*e1.x + e1.y*e1.y + e1.z*e1.z + e1.w*e1.w;
  float sw = w0.x*w0.x + w0.y*w0.y + w0.z*w0.z + w0.w*w0.w
           + w1.x*w1.x + w1.y*w1.y + w1.z*w1.z + w1.w*w1.w;
#pragma unroll
  for (int d = 1; d < 64; d <<= 1) {
    dot += __shfl_xor(dot, d); se += __shfl_xor(se, d); sw += __shfl_xor(sw, d);
  }
  float cosv = dot / (fmaxf(sqrtf(se), 1e-12f) * fmaxf(sqrtf(sw), 1e-12f));
  float cc = fminf(fmaxf(cosv, -1.f), 1.f);
  float sine = sqrtf(fmaxf(1.f - cc * cc, 0.f));
  float phi = (cosv > kTHR) ? (cosv * kCOS_M - sine * kSIN_M) : (cosv - kMM);
  if (l == 0) { lcos[r] = 64.f * cosv; lphi[r] = 64.f * phi; }
}

// ---------------- K3: fused fp8 GEMM + fixed-max expsum (2 blocks/CU) ------
// 512 blocks = 4 panels x 128 cgs, XCD-paired. BM=128 (A resident, 64KB),
// BN=128/phase, BK=64. LDS = 65536 + 16384 = 81920 exactly -> 2 blocks/CU.
// rowsum lives in GLOBAL scratch (same-CU L1; store+vmcnt0 before writer's
// barrier, prefetch 2 regions later). R11's proven one-barrier-per-phase
// schedule; loads 4 phases ahead; no vmcnt in steady-state loop.
__global__ __launch_bounds__(512, 4) void kmain(
    const unsigned char* __restrict__ En8, const float* __restrict__ W,
    float* __restrict__ psum, float* __restrict__ rowsumG)
{
  __shared__ __align__(16) unsigned char Asm[128 * 512];   // 64 KB
  __shared__ __align__(16) unsigned char Bsm[2][8192];     // 16 KB

  int bid = blockIdx.x;
  int xcd = bid & 7;
  int panel = (bid >> 3) & 3;
  int grp = bid >> 5;                        // 0..15
  int cg = xcd | (grp << 3);                 // 0..127

  int tid = threadIdx.x;
  int w = tid >> 6, l = tid & 63;
  int wr = w >> 1, wc = w & 1;               // 4 row-waves x 2 col-waves
  int cl = l & 31, hi = l >> 5;
  int bcls = tid >> 2, bs2 = tid & 3;        // staging: class 0..127, 16-float seg

  int nt = (cg < 14) ? 7 : 6;                // 782 = 6*128 + 14
  int nph = nt * 8;

  // ---- stage A panel once: pure linear glds (source pre-swizzled) ----
#pragma unroll
  for (int i = 0; i < 8; ++i) {
    int base = i * 8192 + w * 1024;
    __builtin_amdgcn_global_load_lds(
        (const __attribute__((address_space(1))) void*)(En8 + panel * 65536 + base + l * 16),
        (__attribute__((address_space(3))) void*)(&Asm[base]), 16, 0, 0);
  }

  float ssq = 0.f;
  // thread's 16 floats = k-segs bs3a=2*bs2 (floats 0-7), bs3b=2*bs2+1 (8-15)
  const int boffA = (bcls >> 6) * 4096 + (bs2 >> 1) * 1024 + (bcls & 63) * 16 + (bs2 & 1) * 8;

  f32x4 Ra[4], Rb[4];
  auto loadB = [&](int q, f32x4* R) {
    int cls = (cg + ((q >> 3) << 7)) * 128 + bcls;
    if (cls >= NCLS) cls = NCLS - 1;
    const float* p = W + (size_t)cls * EMBED + ((q & 7) << 6) + (bs2 << 4);
#pragma unroll
    for (int i = 0; i < 4; ++i) R[i] = *(const f32x4*)(p + i * 4);
  };
  auto writeB = [&](int buf, f32x4* R) {
    float x0 = R[0].x*128.f, x1 = R[0].y*128.f, x2 = R[0].z*128.f, x3 = R[0].w*128.f;
    float x4 = R[1].x*128.f, x5 = R[1].y*128.f, x6 = R[1].z*128.f, x7 = R[1].w*128.f;
    float x8 = R[2].x*128.f, x9 = R[2].y*128.f, xa = R[2].z*128.f, xb = R[2].w*128.f;
    float xc = R[3].x*128.f, xd = R[3].y*128.f, xe = R[3].z*128.f, xf = R[3].w*128.f;
    ssq += x0*x0 + x1*x1 + x2*x2 + x3*x3 + x4*x4 + x5*x5 + x6*x6 + x7*x7
         + x8*x8 + x9*x9 + xa*xa + xb*xb + xc*xc + xd*xd + xe*xe + xf*xf;
    uint2 pA, pB;
    pA.x = cvt4(x0, x1, x2, x3); pA.y = cvt4(x4, x5, x6, x7);
    pB.x = cvt4(x8, x9, xa, xb); pB.y = cvt4(xc, xd, xe, xf);
    *(uint2*)(&Bsm[buf][boffA])        = pA;
    *(uint2*)(&Bsm[buf][boffA + 2048]) = pB;
  };

  f32x16 acc0, acc1, S;
#pragma unroll
  for (int e = 0; e < 16; ++e) { acc0[e] = 0.f; acc1[e] = 0.f; S[e] = 0.f; }

  const unsigned char* Abase = &Asm[(wr * 32 + cl) * 512];
  const unsigned char* Bc0 = &Bsm[0][wc * 4096 + (hi * 2) * 1024 + cl * 16];
  const unsigned char* Bc1 = &Bsm[1][wc * 4096 + (hi * 2) * 1024 + cl * 16];

  auto compute = [&](const unsigned char* bb, int pt) {
    int t0 = pt * 2;
    i64x2 a0 = *(const i64x2*)(Abase + ((((hi << 4) | t0)       ^ cl) << 4));
    i64x2 a1 = *(const i64x2*)(Abase + ((((hi << 4) | (t0 + 1)) ^ cl) << 4));
    i64x2 b0 = *(const i64x2*)(bb);
    i64x2 b1 = *(const i64x2*)(bb + 1024);
    i64x2 c0 = *(const i64x2*)(bb + 512);
    i64x2 c1 = *(const i64x2*)(bb + 1536);
    __builtin_amdgcn_s_setprio(1);
    acc0 = __builtin_amdgcn_mfma_f32_32x32x16_fp8_fp8(a0[0], b0[0], acc0, 0, 0, 0);
    acc0 = __builtin_amdgcn_mfma_f32_32x32x16_fp8_fp8(a0[1], b0[1], acc0, 0, 0, 0);
    acc0 = __builtin_amdgcn_mfma_f32_32x32x16_fp8_fp8(a1[0], b1[0], acc0, 0, 0, 0);
    acc0 = __builtin_amdgcn_mfma_f32_32x32x16_fp8_fp8(a1[1], b1[1], acc0, 0, 0, 0);
    acc1 = __builtin_amdgcn_mfma_f32_32x32x16_fp8_fp8(a0[0], c0[0], acc1, 0, 0, 0);
    acc1 = __builtin_amdgcn_mfma_f32_32x32x16_fp8_fp8(a0[1], c0[1], acc1, 0, 0, 0);
    acc1 = __builtin_amdgcn_mfma_f32_32x32x16_fp8_fp8(a1[0], c1[0], acc1, 0, 0, 0);
    acc1 = __builtin_amdgcn_mfma_f32_32x32x16_fp8_fp8(a1[1], c1[1], acc1, 0, 0, 0);
    __builtin_amdgcn_s_setprio(0);
  };

  // publish per-class ssq to GLOBAL (same-CU L1): store + vmcnt(0) BEFORE the
  // writer's next barrier -> visible to readers after that barrier.
  auto ssqred = [&]() {
    float sq = ssq;
    sq += __shfl_xor(sq, 1); sq += __shfl_xor(sq, 2);
    if (bs2 == 0) rowsumG[bid * 128 + bcls] = sq;
    ssq = 0.f;
    asm volatile("s_waitcnt vmcnt(0)" ::: "memory");
  };

  float Rrs0 = 1.0f, Rrs1 = 1.0f;
  auto epilogue = [&](int T) {
    float rn0 = 4.0f / sqrtf(fmaxf(Rrs0, 1e-30f));
    float rn1 = 4.0f / sqrtf(fmaxf(Rrs1, 1e-30f));
    int base = (cg + (T << 7)) * 128 + wc * 64;
    float vm0 = (base + cl < NCLS) ? 1.0f : 0.0f;
    float vm1 = (base + 32 + cl < NCLS) ? 1.0f : 0.0f;
#pragma unroll
    for (int e = 0; e < 16; ++e) {
      float u0 = __expf(fmaf(acc0[e], rn0, -64.0f));
      float u1 = __expf(fmaf(acc1[e], rn1, -64.0f));
      S[e] = fmaf(u0, vm0, fmaf(u1, vm1, S[e]));
      acc0[e] = 0.f; acc1[e] = 0.f;
    }
  };

  // ---- prologue: stage phases 0,1; regs hold phases 2,3 ----
  loadB(0, Ra); loadB(1, Rb);
  writeB(0, Ra); writeB(1, Rb);
  loadB(2, Ra); loadB(3, Rb);
  asm volatile("s_waitcnt vmcnt(0)" ::: "memory");   // A + Bsm[0/1] staged
  BARRIER();

  for (int p = 0; p < nph; p += 2) {
    // -------- even phase --------
    compute(Bc0, p & 7);
    BARRIER();                                  // readers done with Bsm[0]
    if (p + 2 < nph) writeB(0, Ra);             // stage phase p+2
    if (p + 4 < nph) loadB(p + 4, Ra);
    if ((p & 7) == 6) {                         // prefetch rowsums (written at p==4 tail)
      Rrs0 = rowsumG[bid * 128 + wc * 64 + cl];
      Rrs1 = rowsumG[bid * 128 + wc * 64 + 32 + cl];
    }
    // -------- odd phase --------
    int po = p + 1;
    compute(Bc1, po & 7);
    if ((po & 7) == 7) epilogue(po >> 3);       // uses prefetched Rrs
    BARRIER();                                  // readers done with Bsm[1]
    if (po + 2 < nph) writeB(1, Rb);            // stage phase po+2
    if (((po + 2) & 7) == 7) ssqred();          // tile's 8 chunks staged; store+vmcnt0
    if (po + 4 < nph) loadB(po + 4, Rb);
  }

  // ---- fold S across the 32 class-lanes; write per-col-wave partials ----
#pragma unroll
  for (int e = 0; e < 16; ++e) {
    float v = S[e];
    v += __shfl_xor(v, 1); v += __shfl_xor(v, 2); v += __shfl_xor(v, 4);
    v += __shfl_xor(v, 8); v += __shfl_xor(v, 16);
    S[e] = v;
  }
  if (cl == 0) {
#pragma unroll
    for (int e = 0; e < 16; ++e) {
      int row = wr * 32 + (e & 3) + 8 * (e >> 2) + 4 * hi;
      psum[bid * 256 + wc * 128 + row] = S[e];
    }
  }
}

// ---------------- K4: reduce over 8 XCD siblings x 2 col-waves -------------
__global__ void kred1(const float* __restrict__ psum, float* __restrict__ pp2) {
  int g = blockIdx.x;            // 0..63: panel = g>>4, grp = g&15
  int r = threadIdx.x;           // 128
  int panel = g >> 4, grp = g & 15;
  float s = 0.f;
#pragma unroll
  for (int x = 0; x < 8; ++x) {
    int bid = x | (panel << 3) | (grp << 5);
    s += psum[bid * 256 + r] + psum[bid * 256 + 128 + r];
  }
  pp2[g * 128 + r] = s;
}

// ---------------- K5: final combine + label adjust + NLL mean ----------------
__global__ void kfinal(const float* __restrict__ pp2, const float* __restrict__ lcos,
                       const float* __restrict__ lphi, float* __restrict__ out)
{
  int tid = threadIdx.x;         // 512 = one thread per batch row
  int panel = tid >> 7, rl = tid & 127;
  float S = 0.f;
#pragma unroll
  for (int grp = 0; grp < 16; ++grp)
    S += pp2[(panel * 16 + grp) * 128 + rl];
  float lc = lcos[tid], lp = lphi[tid];
  S = S - __expf(lc - 64.f) + __expf(lp - 64.f);
  float nll = 64.f + __logf(S) - lp;
#pragma unroll
  for (int d = 1; d < 64; d <<= 1) nll += __shfl_xor(nll, d);
  __shared__ float sm[8];
  if ((tid & 63) == 0) sm[tid >> 6] = nll;
  __syncthreads();
  if (tid == 0) {
    float t = 0.f;
    for (int k = 0; k < 8; ++k) t += sm[k];
    out[0] = t * (1.0f / 512.0f);
  }
}

extern "C" void kernel_launch(void* const* d_in, const int* in_sizes, int n_in,
                              void* d_out, int out_size, void* d_ws, size_t ws_size,
                              hipStream_t stream)
{
  const float* E      = (const float*)d_in[0];
  const int*   labels = (const int*)d_in[1];
  const float* W      = (const float*)d_in[2];
  float* out = (float*)d_out;

  char* ws = (char*)d_ws;
  unsigned char* En8 = (unsigned char*)ws;              // 512*512 = 262144 B
  float* psum    = (float*)(ws + 262144);               // 512*256*4 = 524288 B
  float* rowsumG = (float*)(ws + 786432);               // 512*128*4 = 262144 B
  float* pp2     = (float*)(ws + 1048576);              // 64*128*4 = 32768 B
  float* lcos    = (float*)(ws + 1081344);              // 2048 B
  float* lphi    = lcos + BATCH;                        // 2048 B

  knorm_e<<<BATCH, 64, 0, stream>>>(E, En8);
  klabel <<<64, 512, 0, stream>>>(E, W, labels, lcos, lphi);
  kmain  <<<NBLK, 512, 0, stream>>>(En8, W, psum, rowsumG);
  kred1  <<<64, 128, 0, stream>>>(psum, pp2);
  kfinal <<<1, 512, 0, stream>>>(pp2, lcos, lphi, out);
}

// Round 14
// 82.024 us; speedup vs baseline: 1.2550x; 1.1074x over previous
//
#include <hip/hip_runtime.h>
#include <hip/hip_bf16.h>
#include <math.h>

#define BATCH 512
#define EMBED 512
#define NCLS  100000
#define NT128 782          // ceil(100000/128) class tiles
#define NBLK  256          // 2 panels x 128 cgs

typedef __attribute__((ext_vector_type(4)))  float f32x4;
typedef __attribute__((ext_vector_type(16))) float f32x16;
typedef __attribute__((ext_vector_type(2)))  long  i64x2;

constexpr float kCOS_M = 0.8775825618903728f;   // cos(0.5)
constexpr float kSIN_M = 0.4794255386042030f;   // sin(0.5)
constexpr float kTHR   = -0.8775825618903728f;  // cos(pi-0.5)
constexpr float kMM    = 0.2397127693021015f;   // sin(pi-0.5)*0.5

#define BARRIER() asm volatile("s_waitcnt lgkmcnt(0)\n\ts_barrier" ::: "memory")

__device__ __forceinline__ unsigned cvt4(float a, float b, float c, float d) {
  int v = __builtin_amdgcn_cvt_pk_fp8_f32(a, b, 0, false);
  v = __builtin_amdgcn_cvt_pk_fp8_f32(c, d, v, true);
  return (unsigned)v;
}

// ---------------- K1: normalize embeddings -> fp8 x16, hi-split + XOR-swizzled ----
// (R11 verbatim) Element k of row r: slotL = k[3]<<4 | k[8:5], half = k[4];
// physical 16B slot = slotL ^ (r&31); byte = half*8 + k[2:0].
__global__ void knorm_e(const float* __restrict__ E, unsigned char* __restrict__ En8) {
  int r = blockIdx.x;
  int l = threadIdx.x;                       // lane owns elems 8l..8l+7
  const f32x4* src = (const f32x4*)(E + r * EMBED);
  f32x4 a = src[2 * l], b = src[2 * l + 1];
  float ss = a.x*a.x + a.y*a.y + a.z*a.z + a.w*a.w
           + b.x*b.x + b.y*b.y + b.z*b.z + b.w*b.w;
#pragma unroll
  for (int d = 1; d < 64; d <<= 1) ss += __shfl_xor(ss, d);
  float s = 16.0f / fmaxf(sqrtf(ss), 1e-12f);
  uint2 pk;
  pk.x = cvt4(a.x * s, a.y * s, a.z * s, a.w * s);
  pk.y = cvt4(b.x * s, b.y * s, b.z * s, b.w * s);
  int slotL = (l & 1) * 16 + (l >> 2);
  int half  = (l >> 1) & 1;
  *(uint2*)(En8 + r * 512 + (((slotL ^ (r & 31)) << 4) | (half << 3))) = pk;
}

// ---------------- K2: label-column cosine + margin in f32 ----------------
__global__ void klabel(const float* __restrict__ E, const float* __restrict__ W,
                       const int* __restrict__ labels,
                       float* __restrict__ lcos, float* __restrict__ lphi)
{
  int r = blockIdx.x * 8 + (threadIdx.x >> 6);
  int l = threadIdx.x & 63;
  int lbl = labels[r];
  const float* ep = E + (size_t)r * EMBED + l * 8;
  const float* wp = W + (size_t)lbl * EMBED + l * 8;
  f32x4 e0 = *(const f32x4*)ep, e1 = *(const f32x4*)(ep + 4);
  f32x4 w0 = *(const f32x4*)wp, w1 = *(const f32x4*)(wp + 4);
  float dot = e0.x*w0.x + e0.y*w0.y + e0.z*w0.z + e0.w*w0.w
            + e1.x*w1.x + e1.y*w1.y + e1.z*w1.z + e1.w*w1.w;
  float se = e0.x*e0.x + e0.y*e0.y + e0.z*e0.z + e0.w*e0.w
           + e1.x*e1.x + e1.y*e1.y + e1.z*e1.z + e1.w*e1.w;
  float sw = w0.x*w0.x + w0.y*w0.y + w0.z*w0.z + w0.w*w0.w
           + w1.x*w1.x + w1.y*w1.y + w1.z*w1.z + w1.w*w1.w;
#pragma unroll
  for (int d = 1; d < 64; d <<= 1) {
    dot += __shfl_xor(dot, d); se += __shfl_xor(se, d); sw += __shfl_xor(sw, d);
  }
  float cosv = dot / (fmaxf(sqrtf(se), 1e-12f) * fmaxf(sqrtf(sw), 1e-12f));
  float cc = fminf(fmaxf(cosv, -1.f), 1.f);
  float sine = sqrtf(fmaxf(1.f - cc * cc, 0.f));
  float phi = (cosv > kTHR) ? (cosv * kCOS_M - sine * kSIN_M) : (cosv - kMM);
  if (l == 0) { lcos[r] = 64.f * cosv; lphi[r] = 64.f * phi; }
}

// ---------------- K3: fused fp8 GEMM + fixed-max expsum (ring-4 B) ---------
// R11 geometry (BM=256, BN=128/phase, BK=64, 2 panels x 128 cgs, 16 waves)
// with FOUR B-buffers and ONE barrier per 2 phases: region k computes phases
// 2k,2k+1 (bufs 2k%4,(2k+1)%4), writes bufs (2k+2)%4,(2k+3)%4 (last read in
// region k-1, fenced), loads phases 2k+6,2k+7. LDS = 128K A + 32K B = 160 KiB
// exactly; rowsum in global scratch (R13 handoff), psum written directly.
__global__ __launch_bounds__(1024, 4) void kmain(
    const unsigned char* __restrict__ En8, const float* __restrict__ W,
    float* __restrict__ psum, float* __restrict__ rowsumG)
{
  __shared__ __align__(16) unsigned char SH[163840];
  unsigned char* Asm = SH;                         // 131072 B
  unsigned char* Bb0 = SH + 131072;                // 4 x 8192 B
  unsigned char* Bb1 = SH + 131072 + 8192;
  unsigned char* Bb2 = SH + 131072 + 16384;
  unsigned char* Bb3 = SH + 131072 + 24576;

  int bid = blockIdx.x;
  int xcd = bid & 7;
  int panel = (bid >> 3) & 1;
  int grp = bid >> 4;                        // 0..15
  int cg = xcd | (grp << 3);                 // 0..127

  int tid = threadIdx.x;
  int w = tid >> 6, l = tid & 63;
  int wr = w >> 1, wc = w & 1;               // 8 row-waves x 2 col-waves
  int cl = l & 31, hi = l >> 5;
  int bcls = tid >> 3, bs3 = tid & 7;        // B staging: class 0..127, 8-float seg

  int nt = (cg < 14) ? 7 : 6;                // 782 = 6*128 + 14
  int nph = nt * 8;
  int R = nt * 4;                            // regions (always even)

  // ---- stage A panel once: pure linear glds (source pre-swizzled) ----
#pragma unroll
  for (int i = 0; i < 8; ++i) {
    int base = i * 16384 + w * 1024;
    __builtin_amdgcn_global_load_lds(
        (const __attribute__((address_space(1))) void*)(En8 + panel * 131072 + base + l * 16),
        (__attribute__((address_space(3))) void*)(&Asm[base]), 16, 0, 0);
  }

  float ssq = 0.f;
  const int boffA = (bcls >> 6) * 4096 + ((bs3 & 1) * 2 + (bs3 >> 2)) * 1024
                  + (bcls & 63) * 16 + ((bs3 >> 1) & 1) * 8;

  auto loadB = [&](int q, f32x4& v0, f32x4& v1) {
    int cls = (cg + ((q >> 3) << 7)) * 128 + bcls;
    if (cls >= NCLS) cls = NCLS - 1;
    const float* p = W + (size_t)cls * EMBED + ((q & 7) << 6) + bs3 * 8;
    v0 = *(const f32x4*)p;
    v1 = *(const f32x4*)(p + 4);
  };
  auto writeB = [&](unsigned char* buf, f32x4 v0, f32x4 v1) {
    float x0 = v0.x*128.f, x1 = v0.y*128.f, x2 = v0.z*128.f, x3 = v0.w*128.f;
    float x4 = v1.x*128.f, x5 = v1.y*128.f, x6 = v1.z*128.f, x7 = v1.w*128.f;
    ssq += x0*x0 + x1*x1 + x2*x2 + x3*x3 + x4*x4 + x5*x5 + x6*x6 + x7*x7;
    uint2 pk;
    pk.x = cvt4(x0, x1, x2, x3);
    pk.y = cvt4(x4, x5, x6, x7);
    *(uint2*)(buf + boffA) = pk;
  };

  f32x16 acc0, acc1, S;
#pragma unroll
  for (int e = 0; e < 16; ++e) { acc0[e] = 0.f; acc1[e] = 0.f; S[e] = 0.f; }

  const unsigned char* Abase = Asm + (wr * 32 + cl) * 512;
  const int bcol = wc * 4096 + hi * 2048 + cl * 16;
  const unsigned char* Bc0 = Bb0 + bcol;
  const unsigned char* Bc1 = Bb1 + bcol;
  const unsigned char* Bc2 = Bb2 + bcol;
  const unsigned char* Bc3 = Bb3 + bcol;

  auto compute = [&](const unsigned char* bb, int pt) {
    int t0 = pt * 2;
    i64x2 a0 = *(const i64x2*)(Abase + ((((hi << 4) | t0)       ^ cl) << 4));
    i64x2 a1 = *(const i64x2*)(Abase + ((((hi << 4) | (t0 + 1)) ^ cl) << 4));
    i64x2 b0 = *(const i64x2*)(bb);
    i64x2 b1 = *(const i64x2*)(bb + 1024);
    i64x2 c0 = *(const i64x2*)(bb + 512);
    i64x2 c1 = *(const i64x2*)(bb + 1536);
    __builtin_amdgcn_s_setprio(1);
    acc0 = __builtin_amdgcn_mfma_f32_32x32x16_fp8_fp8(a0[0], b0[0], acc0, 0, 0, 0);
    acc0 = __builtin_amdgcn_mfma_f32_32x32x16_fp8_fp8(a0[1], b0[1], acc0, 0, 0, 0);
    acc0 = __builtin_amdgcn_mfma_f32_32x32x16_fp8_fp8(a1[0], b1[0], acc0, 0, 0, 0);
    acc0 = __builtin_amdgcn_mfma_f32_32x32x16_fp8_fp8(a1[1], b1[1], acc0, 0, 0, 0);
    acc1 = __builtin_amdgcn_mfma_f32_32x32x16_fp8_fp8(a0[0], c0[0], acc1, 0, 0, 0);
    acc1 = __builtin_amdgcn_mfma_f32_32x32x16_fp8_fp8(a0[1], c0[1], acc1, 0, 0, 0);
    acc1 = __builtin_amdgcn_mfma_f32_32x32x16_fp8_fp8(a1[0], c1[0], acc1, 0, 0, 0);
    acc1 = __builtin_amdgcn_mfma_f32_32x32x16_fp8_fp8(a1[1], c1[1], acc1, 0, 0, 0);
    __builtin_amdgcn_s_setprio(0);
  };

  // publish per-class ssq (R13 handoff: store + vmcnt(0) before region barrier)
  auto ssqred = [&]() {
    float sq = ssq;
    sq += __shfl_xor(sq, 1); sq += __shfl_xor(sq, 2); sq += __shfl_xor(sq, 4);
    if (bs3 == 0) rowsumG[bid * 128 + bcls] = sq;
    ssq = 0.f;
    asm volatile("s_waitcnt vmcnt(0)" ::: "memory");
  };

  float Rrs0 = 1.0f, Rrs1 = 1.0f;
  auto epilogue = [&](int T) {
    float rn0 = 4.0f / sqrtf(fmaxf(Rrs0, 1e-30f));
    float rn1 = 4.0f / sqrtf(fmaxf(Rrs1, 1e-30f));
    int base = (cg + (T << 7)) * 128 + wc * 64;
    float vm0 = (base + cl < NCLS) ? 1.0f : 0.0f;
    float vm1 = (base + 32 + cl < NCLS) ? 1.0f : 0.0f;
#pragma unroll
    for (int e = 0; e < 16; ++e) {
      float u0 = __expf(fmaf(acc0[e], rn0, -64.0f));
      float u1 = __expf(fmaf(acc1[e], rn1, -64.0f));
      S[e] = fmaf(u0, vm0, fmaf(u1, vm1, S[e]));
      acc0[e] = 0.f; acc1[e] = 0.f;
    }
  };

  // reg banks: bank A feeds even regions, bank B odd regions (2-region depth)
  f32x4 Ae0, Ae1, Ao0, Ao1, Be0, Be1, Bo0, Bo1;

  // ---- prologue ----
  loadB(0, Ae0, Ae1); loadB(1, Ao0, Ao1);
  writeB(Bb0, Ae0, Ae1); writeB(Bb1, Ao0, Ao1);
  loadB(2, Ae0, Ae1); loadB(3, Ao0, Ao1);     // written in region 0 (bufs 2,3)
  loadB(4, Be0, Be1); loadB(5, Bo0, Bo1);     // written in region 1 (bufs 0,1)
  asm volatile("s_waitcnt vmcnt(0)" ::: "memory");   // A + all prologue data in
  BARRIER();

  for (int k = 0; k < R; k += 2) {
    // ===== even region k: compute bufs 0,1; write bufs 2,3; load ph 2k+6/7 =====
    {
      int p0 = 2 * k;
      compute(Bc0, p0 & 7);
      compute(Bc1, (p0 + 1) & 7);
      if (k < R - 1) { writeB(Bb2, Ae0, Ae1); writeB(Bb3, Ao0, Ao1); }
      if ((k & 3) == 2) ssqred();            // tile (2k+3)>>3 fully staged
      loadB(p0 + 6, Ae0, Ae1);
      loadB(p0 + 7, Ao0, Ao1);
      BARRIER();
    }
    // ===== odd region k+1: compute bufs 2,3; write bufs 0,1; load +2 =====
    {
      int p0 = 2 * k + 2;
      bool epi = ((p0 + 1) & 7) == 7;
      if (epi) {                              // rowsum stored last region, fenced
        Rrs0 = rowsumG[bid * 128 + wc * 64 + cl];
        Rrs1 = rowsumG[bid * 128 + wc * 64 + 32 + cl];
      }
      compute(Bc2, p0 & 7);
      compute(Bc3, (p0 + 1) & 7);
      if (epi) epilogue((p0 + 1) >> 3);
      if (k < R - 2) { writeB(Bb0, Be0, Be1); writeB(Bb1, Bo0, Bo1); }
      loadB(p0 + 6, Be0, Be1);
      loadB(p0 + 7, Bo0, Bo1);
      BARRIER();
    }
  }

  // ---- fold S across the 32 class-lanes; write per-col-wave partials ----
#pragma unroll
  for (int e = 0; e < 16; ++e) {
    float v = S[e];
    v += __shfl_xor(v, 1); v += __shfl_xor(v, 2); v += __shfl_xor(v, 4);
    v += __shfl_xor(v, 8); v += __shfl_xor(v, 16);
    S[e] = v;
  }
  if (cl == 0) {
#pragma unroll
    for (int e = 0; e < 16; ++e) {
      int row = wr * 32 + (e & 3) + 8 * (e >> 2) + 4 * hi;
      psum[bid * 512 + wc * 256 + row] = S[e];
    }
  }
}

// ---------------- K4: reduce over 8 XCD siblings x 2 col-waves -------------
__global__ void kred1(const float* __restrict__ psum, float* __restrict__ pp2) {
  int g = blockIdx.x;            // 0..31: panel = g>>4, grp = g&15
  int r = threadIdx.x;           // 256
  int panel = g >> 4, grp = g & 15;
  float s = 0.f;
#pragma unroll
  for (int x = 0; x < 8; ++x) {
    int bid = x | (panel << 3) | (grp << 4);
    s += psum[bid * 512 + r] + psum[bid * 512 + 256 + r];
  }
  pp2[g * 256 + r] = s;
}

// ---------------- K5: final combine + label adjust + NLL mean ----------------
__global__ void kfinal(const float* __restrict__ pp2, const float* __restrict__ lcos,
                       const float* __restrict__ lphi, float* __restrict__ out)
{
  int tid = threadIdx.x;         // 512 = one thread per batch row
  int panel = tid >> 8, rl = tid & 255;
  float S = 0.f;
#pragma unroll
  for (int grp = 0; grp < 16; ++grp)
    S += pp2[(panel * 16 + grp) * 256 + rl];
  float lc = lcos[tid], lp = lphi[tid];
  S = S - __expf(lc - 64.f) + __expf(lp - 64.f);
  float nll = 64.f + __logf(S) - lp;
#pragma unroll
  for (int d = 1; d < 64; d <<= 1) nll += __shfl_xor(nll, d);
  __shared__ float sm[8];
  if ((tid & 63) == 0) sm[tid >> 6] = nll;
  __syncthreads();
  if (tid == 0) {
    float t = 0.f;
    for (int k = 0; k < 8; ++k) t += sm[k];
    out[0] = t * (1.0f / 512.0f);
  }
}

extern "C" void kernel_launch(void* const* d_in, const int* in_sizes, int n_in,
                              void* d_out, int out_size, void* d_ws, size_t ws_size,
                              hipStream_t stream)
{
  const float* E      = (const float*)d_in[0];
  const int*   labels = (const int*)d_in[1];
  const float* W      = (const float*)d_in[2];
  float* out = (float*)d_out;

  char* ws = (char*)d_ws;
  unsigned char* En8 = (unsigned char*)ws;              // 512*512 = 262144 B
  float* psum    = (float*)(ws + 262144);               // 256*512*4 = 524288 B
  float* rowsumG = (float*)(ws + 786432);               // 256*128*4 = 131072 B
  float* pp2     = (float*)(ws + 917504);               // 32*256*4 = 32768 B
  float* lcos    = (float*)(ws + 950272);               // 2048 B
  float* lphi    = lcos + BATCH;                        // 2048 B

  knorm_e<<<BATCH, 64, 0, stream>>>(E, En8);
  klabel <<<64, 512, 0, stream>>>(E, W, labels, lcos, lphi);
  kmain  <<<NBLK, 1024, 0, stream>>>(En8, W, psum, rowsumG);
  kred1  <<<32, 256, 0, stream>>>(psum, pp2);
  kfinal <<<1, 512, 0, stream>>>(pp2, lcos, lphi, out);
}